// Round 10
// baseline (366.397 us; speedup 1.0000x reference)
//
#include <hip/hip_runtime.h>
#include <math.h>

#define N_NODES  50000
#define N_EDGES  800000
#define HID      64
#define OUT_DIM  12
#define N_LAYERS 4
#define N_GRAPHS 512

#define SCAN_CHUNK 512
#define N_CHUNKS   ((N_NODES + SCAN_CHUNK - 1) / SCAN_CHUNK)   // 98

typedef unsigned short u16;
typedef unsigned int   u32;
typedef __attribute__((ext_vector_type(8))) short bf16x8;   // 8 bf16 = 4 VGPRs
typedef __attribute__((ext_vector_type(4))) float f32x4;

#define L2E 1.44269504f   // log2(e), folded into k,q so gate uses exp2 directly

__device__ __forceinline__ u32 f2bf(float f) {
    u32 u = __float_as_uint(f);
    return (u + 0x7FFFu + ((u >> 16) & 1u)) >> 16;   // RNE
}
__device__ __forceinline__ float bf2f(u32 h) {
    return __uint_as_float(h << 16);
}
__device__ __forceinline__ float bf2f_hi(u32 h) {
    return __uint_as_float(h & 0xffff0000u);
}

// ---------------------------------------------------------------------------
// Weight prep (once): wt[m][n][k] bf16, m = layer*4 + {0:q,1:v,2:k,3:s}
// Wq, Wk pre-scaled by log2(e) so the gate exp needs no scale multiply.
// ---------------------------------------------------------------------------
__global__ __launch_bounds__(256) void wprep_kernel(
    const float* __restrict__ Wq, const float* __restrict__ Wv,
    const float* __restrict__ Wk, const float* __restrict__ Ws,
    u16* __restrict__ wt)
{
    int m = blockIdx.x;          // 0..15
    int lyr = m >> 2, j = m & 3;
    const float* src;
    switch (j) { case 0: src = Wq; break; case 1: src = Wv; break;
                 case 2: src = Wk; break; default: src = Ws; }
    src += (size_t)lyr * HID * HID;
    float scale = (j == 0 || j == 2) ? L2E : 1.0f;
    int t  = threadIdx.x;
    int n  = t >> 2;             // output row (col of W)
    int k0 = (t & 3) * 16;       // 16 k per thread
    u32 buf[8];
    #pragma unroll
    for (int i = 0; i < 16; i += 2) {
        float f0 = src[(k0 + i) * HID + n] * scale;
        float f1 = src[(k0 + i + 1) * HID + n] * scale;
        buf[i / 2] = f2bf(f0) | (f2bf(f1) << 16);
    }
    u32* dst = (u32*)(wt + (size_t)m * 4096 + n * 64 + k0);
    *(uint4*)(dst)     = make_uint4(buf[0], buf[1], buf[2], buf[3]);
    *(uint4*)(dst + 4) = make_uint4(buf[4], buf[5], buf[6], buf[7]);
}

// ---------------------------------------------------------------------------
// Layer-0 input convert: f32 -> packed bf16
// ---------------------------------------------------------------------------
__global__ __launch_bounds__(256) void cvt_kernel(
    const float* __restrict__ x, u32* __restrict__ xbf)
{
    int i = blockIdx.x * 256 + threadIdx.x;          // 8 floats per thread
    if (i >= N_NODES * HID / 8) return;
    float4 a = ((const float4*)x)[2 * i];
    float4 b = ((const float4*)x)[2 * i + 1];
    ((uint4*)xbf)[i] = make_uint4(
        f2bf(a.x) | (f2bf(a.y) << 16), f2bf(a.z) | (f2bf(a.w) << 16),
        f2bf(b.x) | (f2bf(b.y) << 16), f2bf(b.z) | (f2bf(b.w) << 16));
}

// ---------------------------------------------------------------------------
// Fused MFMA GEMM: each 64-node block computes all 4 matrices in one pass.
// q,v -> interleaved bf16 qv; k -> packed bf16 kbf; s -> packed bf16 sbf.
// 4 waves x 16 nodes, mfma_f32_16x16x32_bf16, no LDS.
// C/D: col=lane&15, row=(lane>>4)*4+reg.
// ---------------------------------------------------------------------------
__global__ __launch_bounds__(256) void gemm_mfma_kernel(
    const u16* __restrict__ xbf, const u16* __restrict__ wt, int layer,
    const float* __restrict__ bq, const float* __restrict__ bv,
    const float* __restrict__ bk, const float* __restrict__ bs,
    u32* __restrict__ qv, u32* __restrict__ kbf, u32* __restrict__ sbf)
{
    const int t = threadIdx.x;
    const int w = t >> 6;
    const int l = t & 63;
    const int row16 = l & 15;
    const int kgrp  = l >> 4;
    const int gbase = blockIdx.x * 64;

    const u16* wbase = wt + (size_t)layer * 4 * 4096;

    int nodeA = gbase + w * 16 + row16;
    int nodeAc = nodeA < N_NODES ? nodeA : N_NODES - 1;
    bf16x8 a0 = *(const bf16x8*)(xbf + (size_t)nodeAc * 64 + kgrp * 8);
    bf16x8 a1 = *(const bf16x8*)(xbf + (size_t)nodeAc * 64 + 32 + kgrp * 8);

    f32x4 acc[4][4];               // [mat: q,v,k,s][ntile]
    #pragma unroll
    for (int nt = 0; nt < 4; ++nt) {
        int col = nt * 16 + row16;
        float fq = bq[col] * L2E;
        float fv = bv[col];
        float fk = bk[col] * L2E;
        float fs = bs[col];
        acc[0][nt] = (f32x4){fq, fq, fq, fq};
        acc[1][nt] = (f32x4){fv, fv, fv, fv};
        acc[2][nt] = (f32x4){fk, fk, fk, fk};
        acc[3][nt] = (f32x4){fs, fs, fs, fs};
    }

    #pragma unroll
    for (int m = 0; m < 4; ++m) {
        #pragma unroll
        for (int nt = 0; nt < 4; ++nt) {
            const u16* pb = wbase + m * 4096 + (nt * 16 + row16) * 64 + kgrp * 8;
            bf16x8 b0 = *(const bf16x8*)(pb);
            bf16x8 b1 = *(const bf16x8*)(pb + 32);
            acc[m][nt] = __builtin_amdgcn_mfma_f32_16x16x32_bf16(a0, b0, acc[m][nt], 0, 0, 0);
            acc[m][nt] = __builtin_amdgcn_mfma_f32_16x16x32_bf16(a1, b1, acc[m][nt], 0, 0, 0);
        }
    }

    // epilogue: pack adjacent cols (even lane takes odd lane's value via shfl)
    #pragma unroll
    for (int nt = 0; nt < 4; ++nt) {
        #pragma unroll
        for (int r = 0; r < 4; ++r) {
            float qe = acc[0][nt][r]; float qo = __shfl_xor(qe, 1);
            float ve = acc[1][nt][r]; float vo = __shfl_xor(ve, 1);
            float ke = acc[2][nt][r]; float ko = __shfl_xor(ke, 1);
            float se = acc[3][nt][r]; float so = __shfl_xor(se, 1);
            int gn = gbase + w * 16 + kgrp * 4 + r;
            if (!(l & 1) && gn < N_NODES) {
                int col = nt * 16 + row16;      // even
                u32 qp = f2bf(qe) | (f2bf(qo) << 16);
                u32 vp = f2bf(ve) | (f2bf(vo) << 16);
                *(uint2*)(qv + (size_t)gn * 64 + col) = make_uint2(qp, vp);
                int cp = col >> 1;
                kbf[(size_t)gn * 32 + cp] = f2bf(ke) | (f2bf(ko) << 16);
                sbf[(size_t)gn * 32 + cp] = f2bf(se) | (f2bf(so) << 16);
            }
        }
    }
}

// ---------------------------------------------------------------------------
// CSR build: histogram of dst (rank = arrival order), scan, rank-scatter
// ---------------------------------------------------------------------------
__global__ __launch_bounds__(256) void hist_kernel(
    const int* __restrict__ ei, int* __restrict__ deg, int* __restrict__ rank)
{
    int e0 = (blockIdx.x * 256 + threadIdx.x) * 4;
    #pragma unroll
    for (int i = 0; i < 4; ++i) {
        int e = e0 + i;
        if (e < N_EDGES) rank[e] = atomicAdd(&deg[ei[N_EDGES + e]], 1);
    }
}

__global__ __launch_bounds__(SCAN_CHUNK) void scan1_kernel(
    const int* __restrict__ deg, int* __restrict__ base, int* __restrict__ blocksum)
{
    __shared__ int s[SCAN_CHUNK];
    int t = threadIdx.x;
    int i = blockIdx.x * SCAN_CHUNK + t;
    int v = (i < N_NODES) ? deg[i] : 0;
    s[t] = v;
    __syncthreads();
    for (int off = 1; off < SCAN_CHUNK; off <<= 1) {
        int u = (t >= off) ? s[t - off] : 0;
        __syncthreads();
        s[t] += u;
        __syncthreads();
    }
    if (i < N_NODES) base[i] = s[t] - v;              // exclusive
    if (t == SCAN_CHUNK - 1) blocksum[blockIdx.x] = s[t];
}

__global__ __launch_bounds__(128) void scan2_kernel(
    const int* __restrict__ blocksum, int* __restrict__ blockoff)
{
    __shared__ int s[128];
    int t = threadIdx.x;
    int v = (t < N_CHUNKS) ? blocksum[t] : 0;
    s[t] = v;
    __syncthreads();
    for (int off = 1; off < 128; off <<= 1) {
        int u = (t >= off) ? s[t - off] : 0;
        __syncthreads();
        s[t] += u;
        __syncthreads();
    }
    if (t < N_CHUNKS) blockoff[t] = s[t] - v;         // exclusive
}

__global__ __launch_bounds__(SCAN_CHUNK) void scan3_kernel(
    int* __restrict__ base, const int* __restrict__ blockoff)
{
    int i = blockIdx.x * SCAN_CHUNK + threadIdx.x;
    if (i < N_NODES) base[i] += blockoff[blockIdx.x];
    if (i == 0) base[N_NODES] = N_EDGES;
}

__global__ __launch_bounds__(256) void scatter_kernel(
    const int* __restrict__ ei, const int* __restrict__ base,
    const int* __restrict__ rank, int* __restrict__ csr_src)
{
    int e0 = (blockIdx.x * 256 + threadIdx.x) * 4;
    #pragma unroll
    for (int i = 0; i < 4; ++i) {
        int e = e0 + i;
        if (e < N_EDGES)
            csr_src[base[ei[N_EDGES + e]] + rank[e]] = ei[e];
    }
}

// ---------------------------------------------------------------------------
// Gather aggregation + skip + GELU. One wave per node (R8 proven form).
// Lanes 0-31 even edges, 32-63 odd edges; lane covers channels {2c,2c+1}.
// Manual unroll-4. k,skip packed bf16 (k pre-scaled by log2e -> exp2 gate).
// ---------------------------------------------------------------------------
__global__ __launch_bounds__(256) void agg_gelu_kernel(
    const int* __restrict__ base, const int* __restrict__ csr_src,
    const u32* __restrict__ kbf, const u32* __restrict__ qv,
    const u32* __restrict__ sbf, u32* __restrict__ outxbf)
{
    int node = blockIdx.x * 4 + (threadIdx.x >> 6);
    if (node >= N_NODES) return;
    int lane = threadIdx.x & 63;
    int half = lane >> 5;
    int c    = lane & 31;             // channel pair: 2c, 2c+1

    u32 kp = kbf[(size_t)node * 32 + c];
    float kd0 = bf2f(kp & 0xffffu), kd1 = bf2f_hi(kp);
    float acc0 = 0.f, acc1 = 0.f;
    int p0 = base[node];
    int p1 = base[node + 1];

    int p = p0 + half;
    // main: 4 edges per half-wave iteration (8 qv lines in flight per wave)
    for (; p + 6 < p1; p += 8) {
        int s0 = csr_src[p];
        int s1 = csr_src[p + 2];
        int s2 = csr_src[p + 4];
        int s3 = csr_src[p + 6];
        uint2 e0 = *(const uint2*)(qv + (size_t)s0 * 64 + 2 * c);
        uint2 e1 = *(const uint2*)(qv + (size_t)s1 * 64 + 2 * c);
        uint2 e2 = *(const uint2*)(qv + (size_t)s2 * 64 + 2 * c);
        uint2 e3 = *(const uint2*)(qv + (size_t)s3 * 64 + 2 * c);
        float g;
        g = 1.f / (1.f + exp2f(-(kd0 + bf2f(e0.x & 0xffffu)))); acc0 = fmaf(g, bf2f(e0.y & 0xffffu), acc0);
        g = 1.f / (1.f + exp2f(-(kd1 + bf2f_hi(e0.x))));        acc1 = fmaf(g, bf2f_hi(e0.y),        acc1);
        g = 1.f / (1.f + exp2f(-(kd0 + bf2f(e1.x & 0xffffu)))); acc0 = fmaf(g, bf2f(e1.y & 0xffffu), acc0);
        g = 1.f / (1.f + exp2f(-(kd1 + bf2f_hi(e1.x))));        acc1 = fmaf(g, bf2f_hi(e1.y),        acc1);
        g = 1.f / (1.f + exp2f(-(kd0 + bf2f(e2.x & 0xffffu)))); acc0 = fmaf(g, bf2f(e2.y & 0xffffu), acc0);
        g = 1.f / (1.f + exp2f(-(kd1 + bf2f_hi(e2.x))));        acc1 = fmaf(g, bf2f_hi(e2.y),        acc1);
        g = 1.f / (1.f + exp2f(-(kd0 + bf2f(e3.x & 0xffffu)))); acc0 = fmaf(g, bf2f(e3.y & 0xffffu), acc0);
        g = 1.f / (1.f + exp2f(-(kd1 + bf2f_hi(e3.x))));        acc1 = fmaf(g, bf2f_hi(e3.y),        acc1);
    }
    for (; p < p1; p += 2) {
        int s = csr_src[p];
        uint2 qp = *(const uint2*)(qv + (size_t)s * 64 + 2 * c);
        float g0 = 1.f / (1.f + exp2f(-(kd0 + bf2f(qp.x & 0xffffu))));
        float g1 = 1.f / (1.f + exp2f(-(kd1 + bf2f_hi(qp.x))));
        acc0 = fmaf(g0, bf2f(qp.y & 0xffffu), acc0);
        acc1 = fmaf(g1, bf2f_hi(qp.y), acc1);
    }

    acc0 += __shfl_xor(acc0, 32);
    acc1 += __shfl_xor(acc1, 32);

    if (half == 0) {
        u32 sp = sbf[(size_t)node * 32 + c];
        float xo0 = acc0 + bf2f(sp & 0xffffu);
        float xo1 = acc1 + bf2f_hi(sp);
        float g0 = 0.5f * xo0 * (1.f + erff(xo0 * 0.70710678118f));
        float g1 = 0.5f * xo1 * (1.f + erff(xo1 * 0.70710678118f));
        outxbf[(size_t)node * 32 + c] = f2bf(g0) | (f2bf(g1) << 16);
    }
}

// ---------------------------------------------------------------------------
// Graph boundaries from sorted batch
// ---------------------------------------------------------------------------
__global__ __launch_bounds__(256) void bounds_kernel(
    const int* __restrict__ batch, int* __restrict__ start)
{
    int n = blockIdx.x * 256 + threadIdx.x;
    if (n >= N_NODES) return;
    int b  = batch[n];
    int bp = (n == 0) ? -1 : batch[n - 1];
    for (int g = bp + 1; g <= b; ++g) start[g] = n;
    if (n == N_NODES - 1) {
        for (int g = b + 1; g <= N_GRAPHS; ++g) start[g] = N_NODES;
    }
}

// ---------------------------------------------------------------------------
// Mean pool from packed bf16 x: 8 node-streams x 32 chanpairs per block
// ---------------------------------------------------------------------------
__global__ __launch_bounds__(256) void pool2_kernel(
    const u32* __restrict__ xbf, const int* __restrict__ start,
    float* __restrict__ pooled)
{
    int g   = blockIdx.x;
    int t   = threadIdx.x;
    int nid = t >> 5;             // 0..7
    int c   = t & 31;
    int s0 = start[g];
    int s1 = start[g + 1];
    float a0 = 0.f, a1 = 0.f;
    for (int n = s0 + nid; n < s1; n += 8) {
        u32 p = xbf[(size_t)n * 32 + c];
        a0 += bf2f(p & 0xffffu);
        a1 += bf2f(p >> 16);
    }
    __shared__ float red0[8][32], red1[8][32];
    red0[nid][c] = a0; red1[nid][c] = a1;
    __syncthreads();
    if (nid == 0) {
        float t0 = 0.f, t1 = 0.f;
        #pragma unroll
        for (int i = 0; i < 8; ++i) { t0 += red0[i][c]; t1 += red1[i][c]; }
        float cnt = fmaxf((float)(s1 - s0), 1.f);
        *(float2*)(pooled + (size_t)g * HID + 2 * c) = make_float2(t0 / cnt, t1 / cnt);
    }
}

// ---------------------------------------------------------------------------
// Head: h = relu(pooled@W1+b1); out = h@W2+b2. One block per graph.
// ---------------------------------------------------------------------------
__global__ __launch_bounds__(64) void head_kernel(
    const float* __restrict__ pooled,
    const float* __restrict__ w1, const float* __restrict__ b1,
    const float* __restrict__ w2, const float* __restrict__ b2,
    float* __restrict__ out)
{
    int g = blockIdx.x;
    int t = threadIdx.x;
    __shared__ float p[64];
    __shared__ float h[64];
    p[t] = pooled[(size_t)g * HID + t];
    __syncthreads();
    float acc = b1[t];
    #pragma unroll 8
    for (int k = 0; k < HID; ++k) acc = fmaf(p[k], w1[k * HID + t], acc);
    h[t] = fmaxf(acc, 0.f);
    __syncthreads();
    if (t < OUT_DIM) {
        float a2 = b2[t];
        #pragma unroll 8
        for (int k = 0; k < HID; ++k) a2 = fmaf(h[k], w2[k * OUT_DIM + t], a2);
        out[(size_t)g * OUT_DIM + t] = a2;
    }
}

// ---------------------------------------------------------------------------
extern "C" void kernel_launch(void* const* d_in, const int* in_sizes, int n_in,
                              void* d_out, int out_size, void* d_ws, size_t ws_size,
                              hipStream_t stream)
{
    const float* x     = (const float*)d_in[0];
    const int*   ei    = (const int*)d_in[1];
    const int*   batch = (const int*)d_in[2];
    const float* Wk = (const float*)d_in[4];
    const float* bk = (const float*)d_in[5];
    const float* Wq = (const float*)d_in[6];
    const float* bq = (const float*)d_in[7];
    const float* Wv = (const float*)d_in[8];
    const float* bv = (const float*)d_in[9];
    const float* Ws = (const float*)d_in[10];
    const float* bs = (const float*)d_in[11];
    const float* w1 = (const float*)d_in[12];
    const float* b1 = (const float*)d_in[13];
    const float* w2 = (const float*)d_in[14];
    const float* b2 = (const float*)d_in[15];
    float* out = (float*)d_out;

    char* wsb = (char*)d_ws;
    const size_t NF = (size_t)N_NODES * HID;
    u32*   xbf    = (u32*)wsb;                      wsb += NF * 2;   // packed bf16 x
    u32*   bufK   = (u32*)wsb;                      wsb += NF * 2;   // packed bf16 k (pre-scaled)
    u32*   bufSbf = (u32*)wsb;                      wsb += NF * 2;   // packed bf16 skip (also CSR scratch)
    u32*   bufQV  = (u32*)wsb;                      wsb += NF * 4;   // interleaved bf16 q,v
    u16*   wt     = (u16*)wsb;                      wsb += (size_t)16 * 4096 * 2;
    float* pooled = (float*)wsb;                    wsb += (size_t)N_GRAPHS * HID * 4;
    int*   baseI  = (int*)wsb;                      wsb += (N_NODES + 1) * 4;
    int*   csr_src= (int*)wsb;                      wsb += (size_t)N_EDGES * 4;
    int*   startI = (int*)wsb;                      wsb += (N_GRAPHS + 1) * 4;
    // transient CSR scratch inside bufSbf (6.4MB >= 3.4MB needed); bufSbf is
    // first written by gemm layer 0, after the CSR build completes in-stream.
    int* deg      = (int*)bufSbf;
    int* rank     = deg + N_NODES;
    int* blocksum = rank + N_EDGES;
    int* blockoff = blocksum + 128;

    const int gemm_gx = (N_NODES + 63) / 64;            // 782
    const int e4g     = (N_EDGES / 4 + 255) / 256;      // 782
    const int agg_gx  = (N_NODES + 3) / 4;              // 12500
    const int nd_g    = (N_NODES + 255) / 256;          // 196
    const int cvt_g   = ((int)(NF / 8) + 255) / 256;    // 1563

    // ---- one-time prep: weights, x->bf16, CSR, bounds ----
    hipMemsetAsync(deg, 0, (size_t)N_NODES * sizeof(int), stream);
    wprep_kernel<<<16, 256, 0, stream>>>(Wq, Wv, Wk, Ws, wt);
    cvt_kernel<<<cvt_g, 256, 0, stream>>>(x, xbf);
    hist_kernel<<<e4g, 256, 0, stream>>>(ei, deg, rank);
    scan1_kernel<<<N_CHUNKS, SCAN_CHUNK, 0, stream>>>(deg, baseI, blocksum);
    scan2_kernel<<<1, 128, 0, stream>>>(blocksum, blockoff);
    scan3_kernel<<<N_CHUNKS, SCAN_CHUNK, 0, stream>>>(baseI, blockoff);
    scatter_kernel<<<e4g, 256, 0, stream>>>(ei, baseI, rank, csr_src);
    bounds_kernel<<<nd_g, 256, 0, stream>>>(batch, startI);

    // ---- layers ----
    for (int l = 0; l < N_LAYERS; ++l) {
        gemm_mfma_kernel<<<gemm_gx, 256, 0, stream>>>(
            (const u16*)xbf, wt, l,
            bq + (size_t)l * HID, bv + (size_t)l * HID,
            bk + (size_t)l * HID, bs + (size_t)l * HID,
            bufQV, bufK, bufSbf);
        agg_gelu_kernel<<<agg_gx, 256, 0, stream>>>(
            baseI, csr_src, bufK, bufQV, bufSbf, xbf);
    }

    // ---- pool + head ----
    pool2_kernel<<<N_GRAPHS, 256, 0, stream>>>(xbf, startI, pooled);
    head_kernel<<<N_GRAPHS, 64, 0, stream>>>(pooled, w1, b1, w2, b2, out);
}

// Round 11
// 333.835 us; speedup vs baseline: 1.0975x; 1.0975x over previous
//
#include <hip/hip_runtime.h>
#include <math.h>

#define N_NODES  50000
#define N_EDGES  800000
#define HID      64
#define OUT_DIM  12
#define N_LAYERS 4
#define N_GRAPHS 512

#define SCAN_CHUNK 512
#define N_CHUNKS   ((N_NODES + SCAN_CHUNK - 1) / SCAN_CHUNK)   // 98

typedef unsigned short u16;
typedef unsigned int   u32;
typedef __attribute__((ext_vector_type(8))) short bf16x8;   // 8 bf16 = 4 VGPRs
typedef __attribute__((ext_vector_type(4))) float f32x4;

__device__ __forceinline__ u32 f2bf(float f) {
    u32 u = __float_as_uint(f);
    return (u + 0x7FFFu + ((u >> 16) & 1u)) >> 16;   // RNE
}
__device__ __forceinline__ float bf2f(u32 h) {
    return __uint_as_float(h << 16);
}
__device__ __forceinline__ float bf2f_hi(u32 h) {
    return __uint_as_float(h & 0xffff0000u);
}

// ---------------------------------------------------------------------------
// Weight prep (once): wt[m][n][k] bf16, m = layer*4 + {0:q,1:v,2:k,3:s}
// ---------------------------------------------------------------------------
__global__ __launch_bounds__(256) void wprep_kernel(
    const float* __restrict__ Wq, const float* __restrict__ Wv,
    const float* __restrict__ Wk, const float* __restrict__ Ws,
    u16* __restrict__ wt)
{
    int m = blockIdx.x;          // 0..15
    int lyr = m >> 2, j = m & 3;
    const float* src;
    switch (j) { case 0: src = Wq; break; case 1: src = Wv; break;
                 case 2: src = Wk; break; default: src = Ws; }
    src += (size_t)lyr * HID * HID;
    int t  = threadIdx.x;
    int n  = t >> 2;             // output row (col of W)
    int k0 = (t & 3) * 16;       // 16 k per thread
    u32 buf[8];
    #pragma unroll
    for (int i = 0; i < 16; i += 2) {
        float f0 = src[(k0 + i) * HID + n];
        float f1 = src[(k0 + i + 1) * HID + n];
        buf[i / 2] = f2bf(f0) | (f2bf(f1) << 16);
    }
    u32* dst = (u32*)(wt + (size_t)m * 4096 + n * 64 + k0);
    *(uint4*)(dst)     = make_uint4(buf[0], buf[1], buf[2], buf[3]);
    *(uint4*)(dst + 4) = make_uint4(buf[4], buf[5], buf[6], buf[7]);
}

// ---------------------------------------------------------------------------
// Layer-0 input convert: f32 -> packed bf16
// ---------------------------------------------------------------------------
__global__ __launch_bounds__(256) void cvt_kernel(
    const float* __restrict__ x, u32* __restrict__ xbf)
{
    int i = blockIdx.x * 256 + threadIdx.x;          // 8 floats per thread
    if (i >= N_NODES * HID / 8) return;
    float4 a = ((const float4*)x)[2 * i];
    float4 b = ((const float4*)x)[2 * i + 1];
    ((uint4*)xbf)[i] = make_uint4(
        f2bf(a.x) | (f2bf(a.y) << 16), f2bf(a.z) | (f2bf(a.w) << 16),
        f2bf(b.x) | (f2bf(b.y) << 16), f2bf(b.z) | (f2bf(b.w) << 16));
}

// ---------------------------------------------------------------------------
// MFMA GEMM (R8 proven form): blockIdx.y=0 -> (Wq,Wv) -> interleaved bf16 qv
//                             blockIdx.y=1 -> (Wk,Ws) -> packed bf16 kbf, sbf
// 64 nodes per block (4 waves x 16), mfma_f32_16x16x32_bf16, no LDS.
// C/D: col=lane&15, row=(lane>>4)*4+reg.
// ---------------------------------------------------------------------------
__global__ __launch_bounds__(256) void gemm_mfma_kernel(
    const u16* __restrict__ xbf, const u16* __restrict__ wt, int layer,
    const float* __restrict__ bq, const float* __restrict__ bv,
    const float* __restrict__ bk, const float* __restrict__ bs,
    u32* __restrict__ qv, u32* __restrict__ kbf, u32* __restrict__ sbf)
{
    const int t = threadIdx.x;
    const int w = t >> 6;
    const int l = t & 63;
    const int row16 = l & 15;
    const int kgrp  = l >> 4;
    const int gbase = blockIdx.x * 64;

    const u16 *wA, *wB; const float *bA, *bB;
    if (blockIdx.y == 0) { wA = wt + (size_t)(layer * 4 + 0) * 4096; bA = bq;
                           wB = wt + (size_t)(layer * 4 + 1) * 4096; bB = bv; }
    else                 { wA = wt + (size_t)(layer * 4 + 2) * 4096; bA = bk;
                           wB = wt + (size_t)(layer * 4 + 3) * 4096; bB = bs; }

    int nodeA = gbase + w * 16 + row16;
    int nodeAc = nodeA < N_NODES ? nodeA : N_NODES - 1;
    bf16x8 a0 = *(const bf16x8*)(xbf + (size_t)nodeAc * 64 + kgrp * 8);
    bf16x8 a1 = *(const bf16x8*)(xbf + (size_t)nodeAc * 64 + 32 + kgrp * 8);

    f32x4 acc[2][4];
    #pragma unroll
    for (int nt = 0; nt < 4; ++nt) {
        float fa = bA[nt * 16 + row16];
        float fb = bB[nt * 16 + row16];
        acc[0][nt] = (f32x4){fa, fa, fa, fa};
        acc[1][nt] = (f32x4){fb, fb, fb, fb};
    }

    #pragma unroll
    for (int nt = 0; nt < 4; ++nt) {
        const u16* pa = wA + (nt * 16 + row16) * 64 + kgrp * 8;
        const u16* pb = wB + (nt * 16 + row16) * 64 + kgrp * 8;
        bf16x8 ba0 = *(const bf16x8*)(pa);
        bf16x8 ba1 = *(const bf16x8*)(pa + 32);
        bf16x8 bb0 = *(const bf16x8*)(pb);
        bf16x8 bb1 = *(const bf16x8*)(pb + 32);
        acc[0][nt] = __builtin_amdgcn_mfma_f32_16x16x32_bf16(a0, ba0, acc[0][nt], 0, 0, 0);
        acc[0][nt] = __builtin_amdgcn_mfma_f32_16x16x32_bf16(a1, ba1, acc[0][nt], 0, 0, 0);
        acc[1][nt] = __builtin_amdgcn_mfma_f32_16x16x32_bf16(a0, bb0, acc[1][nt], 0, 0, 0);
        acc[1][nt] = __builtin_amdgcn_mfma_f32_16x16x32_bf16(a1, bb1, acc[1][nt], 0, 0, 0);
    }

    if (blockIdx.y == 0) {
        // pack adjacent cols (2c,2c+1) into u32 bf16 pairs; interleave q,v
        #pragma unroll
        for (int nt = 0; nt < 4; ++nt) {
            #pragma unroll
            for (int r = 0; r < 4; ++r) {
                float qe = acc[0][nt][r];
                float qo = __shfl_xor(qe, 1);
                float ve = acc[1][nt][r];
                float vo = __shfl_xor(ve, 1);
                if (!(l & 1)) {
                    int gn = gbase + w * 16 + kgrp * 4 + r;
                    if (gn < N_NODES) {
                        u32 qp = f2bf(qe) | (f2bf(qo) << 16);
                        u32 vp = f2bf(ve) | (f2bf(vo) << 16);
                        *(uint2*)(qv + (size_t)gn * 64 + nt * 16 + row16) = make_uint2(qp, vp);
                    }
                }
            }
        }
    } else {
        // k and s packed bf16 pairs
        #pragma unroll
        for (int nt = 0; nt < 4; ++nt) {
            #pragma unroll
            for (int r = 0; r < 4; ++r) {
                float ke = acc[0][nt][r]; float ko = __shfl_xor(ke, 1);
                float se = acc[1][nt][r]; float so = __shfl_xor(se, 1);
                int gn = gbase + w * 16 + kgrp * 4 + r;
                if (!(l & 1) && gn < N_NODES) {
                    int cp = (nt * 16 + row16) >> 1;
                    kbf[(size_t)gn * 32 + cp] = f2bf(ke) | (f2bf(ko) << 16);
                    sbf[(size_t)gn * 32 + cp] = f2bf(se) | (f2bf(so) << 16);
                }
            }
        }
    }
}

// ---------------------------------------------------------------------------
// CSR build: histogram of dst (rank = arrival order), scan, rank-scatter
// ---------------------------------------------------------------------------
__global__ __launch_bounds__(256) void hist_kernel(
    const int* __restrict__ ei, int* __restrict__ deg, int* __restrict__ rank)
{
    int e0 = (blockIdx.x * 256 + threadIdx.x) * 4;
    #pragma unroll
    for (int i = 0; i < 4; ++i) {
        int e = e0 + i;
        if (e < N_EDGES) rank[e] = atomicAdd(&deg[ei[N_EDGES + e]], 1);
    }
}

__global__ __launch_bounds__(SCAN_CHUNK) void scan1_kernel(
    const int* __restrict__ deg, int* __restrict__ base, int* __restrict__ blocksum)
{
    __shared__ int s[SCAN_CHUNK];
    int t = threadIdx.x;
    int i = blockIdx.x * SCAN_CHUNK + t;
    int v = (i < N_NODES) ? deg[i] : 0;
    s[t] = v;
    __syncthreads();
    for (int off = 1; off < SCAN_CHUNK; off <<= 1) {
        int u = (t >= off) ? s[t - off] : 0;
        __syncthreads();
        s[t] += u;
        __syncthreads();
    }
    if (i < N_NODES) base[i] = s[t] - v;              // exclusive
    if (t == SCAN_CHUNK - 1) blocksum[blockIdx.x] = s[t];
}

__global__ __launch_bounds__(128) void scan2_kernel(
    const int* __restrict__ blocksum, int* __restrict__ blockoff)
{
    __shared__ int s[128];
    int t = threadIdx.x;
    int v = (t < N_CHUNKS) ? blocksum[t] : 0;
    s[t] = v;
    __syncthreads();
    for (int off = 1; off < 128; off <<= 1) {
        int u = (t >= off) ? s[t - off] : 0;
        __syncthreads();
        s[t] += u;
        __syncthreads();
    }
    if (t < N_CHUNKS) blockoff[t] = s[t] - v;         // exclusive
}

__global__ __launch_bounds__(SCAN_CHUNK) void scan3_kernel(
    int* __restrict__ base, const int* __restrict__ blockoff)
{
    int i = blockIdx.x * SCAN_CHUNK + threadIdx.x;
    if (i < N_NODES) base[i] += blockoff[blockIdx.x];
    if (i == 0) base[N_NODES] = N_EDGES;
}

__global__ __launch_bounds__(256) void scatter_kernel(
    const int* __restrict__ ei, const int* __restrict__ base,
    const int* __restrict__ rank, int* __restrict__ csr_src)
{
    int e0 = (blockIdx.x * 256 + threadIdx.x) * 4;
    #pragma unroll
    for (int i = 0; i < 4; ++i) {
        int e = e0 + i;
        if (e < N_EDGES)
            csr_src[base[ei[N_EDGES + e]] + rank[e]] = ei[e];
    }
}

// ---------------------------------------------------------------------------
// Gather aggregation + skip + GELU. One wave per node (R8 proven form).
// Lanes 0-31 even edges, 32-63 odd edges; lane covers channels {2c,2c+1}.
// Manual unroll-4 (8 qv lines in flight per wave). __expf gate (fast path).
// k, skip packed bf16; output packed bf16.
// ---------------------------------------------------------------------------
__global__ __launch_bounds__(256) void agg_gelu_kernel(
    const int* __restrict__ base, const int* __restrict__ csr_src,
    const u32* __restrict__ kbf, const u32* __restrict__ qv,
    const u32* __restrict__ sbf, u32* __restrict__ outxbf)
{
    int node = blockIdx.x * 4 + (threadIdx.x >> 6);
    if (node >= N_NODES) return;
    int lane = threadIdx.x & 63;
    int half = lane >> 5;
    int c    = lane & 31;             // channel pair: 2c, 2c+1

    u32 kp = kbf[(size_t)node * 32 + c];
    float kd0 = bf2f(kp & 0xffffu), kd1 = bf2f_hi(kp);
    float acc0 = 0.f, acc1 = 0.f;
    int p0 = base[node];
    int p1 = base[node + 1];

    int p = p0 + half;
    // main: 4 edges per half-wave iteration
    for (; p + 6 < p1; p += 8) {
        int s0 = csr_src[p];
        int s1 = csr_src[p + 2];
        int s2 = csr_src[p + 4];
        int s3 = csr_src[p + 6];
        uint2 e0 = *(const uint2*)(qv + (size_t)s0 * 64 + 2 * c);
        uint2 e1 = *(const uint2*)(qv + (size_t)s1 * 64 + 2 * c);
        uint2 e2 = *(const uint2*)(qv + (size_t)s2 * 64 + 2 * c);
        uint2 e3 = *(const uint2*)(qv + (size_t)s3 * 64 + 2 * c);
        float g;
        g = 1.f / (1.f + __expf(-(kd0 + bf2f(e0.x & 0xffffu)))); acc0 = fmaf(g, bf2f(e0.y & 0xffffu), acc0);
        g = 1.f / (1.f + __expf(-(kd1 + bf2f_hi(e0.x))));        acc1 = fmaf(g, bf2f_hi(e0.y),        acc1);
        g = 1.f / (1.f + __expf(-(kd0 + bf2f(e1.x & 0xffffu)))); acc0 = fmaf(g, bf2f(e1.y & 0xffffu), acc0);
        g = 1.f / (1.f + __expf(-(kd1 + bf2f_hi(e1.x))));        acc1 = fmaf(g, bf2f_hi(e1.y),        acc1);
        g = 1.f / (1.f + __expf(-(kd0 + bf2f(e2.x & 0xffffu)))); acc0 = fmaf(g, bf2f(e2.y & 0xffffu), acc0);
        g = 1.f / (1.f + __expf(-(kd1 + bf2f_hi(e2.x))));        acc1 = fmaf(g, bf2f_hi(e2.y),        acc1);
        g = 1.f / (1.f + __expf(-(kd0 + bf2f(e3.x & 0xffffu)))); acc0 = fmaf(g, bf2f(e3.y & 0xffffu), acc0);
        g = 1.f / (1.f + __expf(-(kd1 + bf2f_hi(e3.x))));        acc1 = fmaf(g, bf2f_hi(e3.y),        acc1);
    }
    for (; p < p1; p += 2) {
        int s = csr_src[p];
        uint2 qp = *(const uint2*)(qv + (size_t)s * 64 + 2 * c);
        float g0 = 1.f / (1.f + __expf(-(kd0 + bf2f(qp.x & 0xffffu))));
        float g1 = 1.f / (1.f + __expf(-(kd1 + bf2f_hi(qp.x))));
        acc0 = fmaf(g0, bf2f(qp.y & 0xffffu), acc0);
        acc1 = fmaf(g1, bf2f_hi(qp.y), acc1);
    }

    acc0 += __shfl_xor(acc0, 32);
    acc1 += __shfl_xor(acc1, 32);

    if (half == 0) {
        u32 sp = sbf[(size_t)node * 32 + c];
        float xo0 = acc0 + bf2f(sp & 0xffffu);
        float xo1 = acc1 + bf2f_hi(sp);
        float g0 = 0.5f * xo0 * (1.f + erff(xo0 * 0.70710678118f));
        float g1 = 0.5f * xo1 * (1.f + erff(xo1 * 0.70710678118f));
        outxbf[(size_t)node * 32 + c] = f2bf(g0) | (f2bf(g1) << 16);
    }
}

// ---------------------------------------------------------------------------
// Graph boundaries from sorted batch
// ---------------------------------------------------------------------------
__global__ __launch_bounds__(256) void bounds_kernel(
    const int* __restrict__ batch, int* __restrict__ start)
{
    int n = blockIdx.x * 256 + threadIdx.x;
    if (n >= N_NODES) return;
    int b  = batch[n];
    int bp = (n == 0) ? -1 : batch[n - 1];
    for (int g = bp + 1; g <= b; ++g) start[g] = n;
    if (n == N_NODES - 1) {
        for (int g = b + 1; g <= N_GRAPHS; ++g) start[g] = N_NODES;
    }
}

// ---------------------------------------------------------------------------
// Mean pool from packed bf16 x: 16 node-streams x 16 chan-quads per block
// ---------------------------------------------------------------------------
__global__ __launch_bounds__(256) void pool2_kernel(
    const u32* __restrict__ xbf, const int* __restrict__ start,
    float* __restrict__ pooled)
{
    int g   = blockIdx.x;
    int t   = threadIdx.x;
    int nid = t >> 4;             // 0..15
    int c4  = t & 15;             // channels 4*c4 .. 4*c4+3
    int s0 = start[g];
    int s1 = start[g + 1];
    float a0 = 0.f, a1 = 0.f, a2 = 0.f, a3 = 0.f;
    for (int n = s0 + nid; n < s1; n += 16) {
        uint2 p = *(const uint2*)(xbf + (size_t)n * 32 + 2 * c4);
        a0 += bf2f(p.x & 0xffffu); a1 += bf2f_hi(p.x);
        a2 += bf2f(p.y & 0xffffu); a3 += bf2f_hi(p.y);
    }
    __shared__ float4 red[16][16];
    red[nid][c4] = make_float4(a0, a1, a2, a3);
    __syncthreads();
    if (nid == 0) {
        float4 s = red[0][c4];
        #pragma unroll
        for (int i = 1; i < 16; ++i) {
            float4 r = red[i][c4];
            s.x += r.x; s.y += r.y; s.z += r.z; s.w += r.w;
        }
        float cnt = fmaxf((float)(s1 - s0), 1.f);
        *(float4*)(pooled + (size_t)g * HID + 4 * c4) =
            make_float4(s.x / cnt, s.y / cnt, s.z / cnt, s.w / cnt);
    }
}

// ---------------------------------------------------------------------------
// Head: h = relu(pooled@W1+b1); out = h@W2+b2. One block per graph.
// ---------------------------------------------------------------------------
__global__ __launch_bounds__(64) void head_kernel(
    const float* __restrict__ pooled,
    const float* __restrict__ w1, const float* __restrict__ b1,
    const float* __restrict__ w2, const float* __restrict__ b2,
    float* __restrict__ out)
{
    int g = blockIdx.x;
    int t = threadIdx.x;
    __shared__ float p[64];
    __shared__ float h[64];
    p[t] = pooled[(size_t)g * HID + t];
    __syncthreads();
    float acc = b1[t];
    #pragma unroll 8
    for (int k = 0; k < HID; ++k) acc = fmaf(p[k], w1[k * HID + t], acc);
    h[t] = fmaxf(acc, 0.f);
    __syncthreads();
    if (t < OUT_DIM) {
        float a2 = b2[t];
        #pragma unroll 8
        for (int k = 0; k < HID; ++k) a2 = fmaf(h[k], w2[k * OUT_DIM + t], a2);
        out[(size_t)g * OUT_DIM + t] = a2;
    }
}

// ---------------------------------------------------------------------------
extern "C" void kernel_launch(void* const* d_in, const int* in_sizes, int n_in,
                              void* d_out, int out_size, void* d_ws, size_t ws_size,
                              hipStream_t stream)
{
    const float* x     = (const float*)d_in[0];
    const int*   ei    = (const int*)d_in[1];
    const int*   batch = (const int*)d_in[2];
    const float* Wk = (const float*)d_in[4];
    const float* bk = (const float*)d_in[5];
    const float* Wq = (const float*)d_in[6];
    const float* bq = (const float*)d_in[7];
    const float* Wv = (const float*)d_in[8];
    const float* bv = (const float*)d_in[9];
    const float* Ws = (const float*)d_in[10];
    const float* bs = (const float*)d_in[11];
    const float* w1 = (const float*)d_in[12];
    const float* b1 = (const float*)d_in[13];
    const float* w2 = (const float*)d_in[14];
    const float* b2 = (const float*)d_in[15];
    float* out = (float*)d_out;

    char* wsb = (char*)d_ws;
    const size_t NF = (size_t)N_NODES * HID;
    u32*   xbf    = (u32*)wsb;                      wsb += NF * 2;   // packed bf16 x
    u32*   bufK   = (u32*)wsb;                      wsb += NF * 2;   // packed bf16 k
    u32*   bufSbf = (u32*)wsb;                      wsb += NF * 2;   // packed bf16 skip (also CSR scratch)
    u32*   bufQV  = (u32*)wsb;                      wsb += NF * 4;   // interleaved bf16 q,v
    u16*   wt     = (u16*)wsb;                      wsb += (size_t)16 * 4096 * 2;
    float* pooled = (float*)wsb;                    wsb += (size_t)N_GRAPHS * HID * 4;
    int*   baseI  = (int*)wsb;                      wsb += (N_NODES + 1) * 4;
    int*   csr_src= (int*)wsb;                      wsb += (size_t)N_EDGES * 4;
    int*   startI = (int*)wsb;                      wsb += (N_GRAPHS + 1) * 4;
    // transient CSR scratch inside bufSbf (6.4MB >= 3.4MB needed); bufSbf is
    // first written by gemm layer 0, after the CSR build completes in-stream.
    int* deg      = (int*)bufSbf;
    int* rank     = deg + N_NODES;
    int* blocksum = rank + N_EDGES;
    int* blockoff = blocksum + 128;

    const int gemm_gx = (N_NODES + 63) / 64;            // 782
    const int e4g     = (N_EDGES / 4 + 255) / 256;      // 782
    const int agg_gx  = (N_NODES + 3) / 4;              // 12500
    const int nd_g    = (N_NODES + 255) / 256;          // 196
    const int cvt_g   = ((int)(NF / 8) + 255) / 256;    // 1563

    // ---- one-time prep: weights, x->bf16, CSR, bounds ----
    hipMemsetAsync(deg, 0, (size_t)N_NODES * sizeof(int), stream);
    wprep_kernel<<<16, 256, 0, stream>>>(Wq, Wv, Wk, Ws, wt);
    cvt_kernel<<<cvt_g, 256, 0, stream>>>(x, xbf);
    hist_kernel<<<e4g, 256, 0, stream>>>(ei, deg, rank);
    scan1_kernel<<<N_CHUNKS, SCAN_CHUNK, 0, stream>>>(deg, baseI, blocksum);
    scan2_kernel<<<1, 128, 0, stream>>>(blocksum, blockoff);
    scan3_kernel<<<N_CHUNKS, SCAN_CHUNK, 0, stream>>>(baseI, blockoff);
    scatter_kernel<<<e4g, 256, 0, stream>>>(ei, baseI, rank, csr_src);
    bounds_kernel<<<nd_g, 256, 0, stream>>>(batch, startI);

    // ---- layers ----
    for (int l = 0; l < N_LAYERS; ++l) {
        gemm_mfma_kernel<<<dim3(gemm_gx, 2), 256, 0, stream>>>(
            (const u16*)xbf, wt, l,
            bq + (size_t)l * HID, bv + (size_t)l * HID,
            bk + (size_t)l * HID, bs + (size_t)l * HID,
            bufQV, bufK, bufSbf);
        agg_gelu_kernel<<<agg_gx, 256, 0, stream>>>(
            baseI, csr_src, bufK, bufQV, bufSbf, xbf);
    }

    // ---- pool + head ----
    pool2_kernel<<<N_GRAPHS, 256, 0, stream>>>(xbf, startI, pooled);
    head_kernel<<<N_GRAPHS, 64, 0, stream>>>(pooled, w1, b1, w2, b2, out);
}